// Round 6
// baseline (290.952 us; speedup 1.0000x reference)
//
#include <hip/hip_runtime.h>
#include <math.h>

#define D 128
#define MAXNORM 0.996f            // (1 - 4e-3)/sqrt(c), c = 1
#define MINNORM 1e-15f
#define ATCLAMP (1.0f - 1e-7f)

#define CHUNK 2048                // edges per sort block (8 per thread)
#define BSH   7                   // 128 nodes per bucket
#define MAXNB 1024                // supports N <= 131072 (problem: N = 100000)
#define CAP   4096                // records per bucket slot (2x mean load)
#define SCAP2 5120                // ks3 LDS staging capacity
#define OCAP  262144              // overflow list capacity
#define TCAP  (1 << 20)           // tail region records (giant-bucket spill)
#define CURSTRIDE 16              // cursor padding: 1 cursor per 64B line

typedef unsigned int   u32;
typedef unsigned short u16;

typedef __attribute__((ext_vector_type(8))) short bf16x8;
typedef __attribute__((ext_vector_type(4))) float f32x4;

__device__ __forceinline__ float wsum(float v) {
#pragma unroll
  for (int m = 32; m; m >>= 1) v += __shfl_xor(v, m);
  return v;
}
// 16-lane reduction (stays within a lane&48 group) — matches MFMA C-layout rows
__device__ __forceinline__ float rsum16(float v) {
#pragma unroll
  for (int m = 1; m <= 8; m <<= 1) v += __shfl_xor(v, m);
  return v;
}

__device__ __forceinline__ float frcp(float x) { return __builtin_amdgcn_rcpf(x); }

// fast artanh for x in [0, 1-1e-7]
__device__ __forceinline__ float fast_artanh(float x) {
  x = fminf(x, ATCLAMP);
  return 0.5f * __logf((1.0f + x) * frcp(1.0f - x));
}
// fast tanh for z >= 0
__device__ __forceinline__ float fast_tanh(float z) {
  float t = __expf(-2.0f * z);
  return (1.0f - t) * frcp(1.0f + t);
}

__device__ __forceinline__ float bflo(u32 u) { return __uint_as_float(u << 16); }
__device__ __forceinline__ float bfhi(u32 u) { return __uint_as_float(u & 0xffff0000u); }
__device__ __forceinline__ u16 f2bf(float f) {            // RNE f32 -> bf16
  u32 u = __float_as_uint(f);
  return (u16)((u + 0x7fffu + ((u >> 16) & 1u)) >> 16);
}
__device__ __forceinline__ float bf2f(u16 h) { return __uint_as_float(((u32)h) << 16); }

union U4B8 { uint4 u; bf16x8 b; };
__device__ __forceinline__ bf16x8 as_b8(uint4 v) { U4B8 c; c.u = v; return c.b; }

// ---- runtime dtype detection (wave-uniform; call before any divergence) ----
__device__ __forceinline__ bool detect_bf16(const u32* p) {
  float lo = fabsf(bflo(p[threadIdx.x & 63]));
  return (bool)__all(lo < 1.0f);
}
__device__ __forceinline__ bool detect_i64(const int* p) {
  return (bool)__all(p[2 * (threadIdx.x & 63) + 1] == 0);
}

// ---------------- K0: zero int buffer ----------------
extern "C" __global__ __launch_bounds__(256) void k0_zeroi(int* p, int n) {
  int i = blockIdx.x * 256 + threadIdx.x;
  if (i < n) p[i] = 0;
}

// ====== K1: MFMA mobius_matvec + proj + mobius_add(bias) + proj + logmap0 ======
// (math verified rounds 1-5) PERSISTENT blocks: W staged in LDS once, then
// grid-stride loop over 16-row tiles (~3 tiles/block) — cuts W-read+convert 3x.
// One 16x128 output tile per wave via mfma_f32_16x16x32_bf16; fp32 path uses
// bf16x3 split. C layout (m89-verified): col = lane&15, row = (lane>>4)*4 + reg.
template<bool BF>
__device__ __forceinline__ void k1_body(const void* xv, const void* Wv,
                                        const void* bv, u16* xt, int N,
                                        uint4* Wh, uint4* Wl) {
  const int tid  = threadIdx.x;
  const int lane = tid & 63;
  const int wid  = tid >> 6;
  const int qg   = lane >> 4;   // k-block group 0..3
  const int lc   = lane & 15;   // col within 16-wide tile

  for (int slot = tid; slot < 2048; slot += 256) {
    const int l = slot & 63, frag = slot >> 6;
    const int t = frag >> 2, ks = frag & 3;
    const int j  = (l & 15) + 16 * t;
    const int k0 = 32 * ks + 8 * (l >> 4);
    if (BF) {
      Wh[slot] = ((const uint4*)Wv)[j * 16 + (k0 >> 3)];
    } else {
      const float* Wf = (const float*)Wv;
      float4 f0 = *(const float4*)(Wf + (size_t)j * D + k0);
      float4 f1 = *(const float4*)(Wf + (size_t)j * D + k0 + 4);
      float f[8] = {f0.x, f0.y, f0.z, f0.w, f1.x, f1.y, f1.z, f1.w};
      u32 hw[4], lw[4];
#pragma unroll
      for (int i = 0; i < 4; ++i) {
        u16 h0 = f2bf(f[2*i]),  h1 = f2bf(f[2*i+1]);
        u16 l0 = f2bf(f[2*i]   - bf2f(h0));
        u16 l1 = f2bf(f[2*i+1] - bf2f(h1));
        hw[i] = (u32)h0 | ((u32)h1 << 16);
        lw[i] = (u32)l0 | ((u32)l1 << 16);
      }
      Wh[slot] = make_uint4(hw[0], hw[1], hw[2], hw[3]);
      Wl[slot] = make_uint4(lw[0], lw[1], lw[2], lw[3]);
    }
  }

  float bfr[8];
  float nb2 = 0.f;
#pragma unroll
  for (int t = 0; t < 8; ++t) {
    float v = BF ? bf2f(((const u16*)bv)[lc + 16 * t])
                 : ((const float*)bv)[lc + 16 * t];
    bfr[t] = v; nb2 += v * v;
  }
  nb2 = rsum16(nb2);
  float y2;
  {
    float nb = fmaxf(sqrtf(nb2), MINNORM);
    float s  = fast_tanh(nb) * frcp(nb);
    float n1 = s * nb;
    if (n1 > MAXNORM) s *= MAXNORM * frcp(n1);
#pragma unroll
    for (int t = 0; t < 8; ++t) bfr[t] *= s;
    y2 = s * s * nb2;
  }
  const bool bias_zero = (y2 == 0.0f);

  __syncthreads();

  const int T = (N + 15) >> 4;
  for (int tile = blockIdx.x * 4 + wid; tile < T; tile += gridDim.x * 4) {
    const int rbase = tile * 16;

    int rowA = rbase + lc; if (rowA >= N) rowA = N - 1;
    uint4 Ah[4], Al[4];
    float xn2 = 0.f;
    if (BF) {
      const uint4* xr = (const uint4*)((const u16*)xv + (size_t)rowA * D);
#pragma unroll
      for (int ks = 0; ks < 4; ++ks) {
        uint4 v = xr[4 * ks + qg];
        Ah[ks] = v;
        float a0 = bflo(v.x), a1 = bfhi(v.x), a2 = bflo(v.y), a3 = bfhi(v.y);
        float a4 = bflo(v.z), a5 = bfhi(v.z), a6 = bflo(v.w), a7 = bfhi(v.w);
        xn2 += a0*a0 + a1*a1 + a2*a2 + a3*a3 + a4*a4 + a5*a5 + a6*a6 + a7*a7;
      }
    } else {
      const float4* xr = (const float4*)((const float*)xv + (size_t)rowA * D);
#pragma unroll
      for (int ks = 0; ks < 4; ++ks) {
        float4 f0 = xr[8 * ks + 2 * qg], f1 = xr[8 * ks + 2 * qg + 1];
        float f[8] = {f0.x, f0.y, f0.z, f0.w, f1.x, f1.y, f1.z, f1.w};
        u32 hw[4], lw[4];
#pragma unroll
        for (int i = 0; i < 4; ++i) {
          u16 h0 = f2bf(f[2*i]),  h1 = f2bf(f[2*i+1]);
          u16 l0 = f2bf(f[2*i]   - bf2f(h0));
          u16 l1 = f2bf(f[2*i+1] - bf2f(h1));
          hw[i] = (u32)h0 | ((u32)h1 << 16);
          lw[i] = (u32)l0 | ((u32)l1 << 16);
          xn2 += f[2*i] * f[2*i] + f[2*i+1] * f[2*i+1];
        }
        Ah[ks] = make_uint4(hw[0], hw[1], hw[2], hw[3]);
        Al[ks] = make_uint4(lw[0], lw[1], lw[2], lw[3]);
      }
    }
    xn2 += __shfl_xor(xn2, 16);
    xn2 += __shfl_xor(xn2, 32);

    f32x4 acc[8];
    const f32x4 zero = {0.f, 0.f, 0.f, 0.f};
#pragma unroll
    for (int t = 0; t < 8; ++t) acc[t] = zero;
#pragma unroll
    for (int ks = 0; ks < 4; ++ks) {
      bf16x8 a = as_b8(Ah[ks]);
      bf16x8 al;
      if (!BF) al = as_b8(Al[ks]);
#pragma unroll
      for (int t = 0; t < 8; ++t) {
        const int idx = (t * 4 + ks) * 64 + lane;
        bf16x8 bh = as_b8(Wh[idx]);
        acc[t] = __builtin_amdgcn_mfma_f32_16x16x32_bf16(a, bh, acc[t], 0, 0, 0);
        if (!BF) {
          bf16x8 bl = as_b8(Wl[idx]);
          acc[t] = __builtin_amdgcn_mfma_f32_16x16x32_bf16(al, bh, acc[t], 0, 0, 0);
          acc[t] = __builtin_amdgcn_mfma_f32_16x16x32_bf16(a,  bl, acc[t], 0, 0, 0);
        }
      }
    }

#pragma unroll
    for (int q = 0; q < 4; ++q) {
      const int row_off = qg * 4 + q;
      const int row = rbase + row_off;
      float xnq = fmaxf(sqrtf(__shfl(xn2, row_off)), MINNORM);
      float s2 = 0.f;
#pragma unroll
      for (int t = 0; t < 8; ++t) { float v = acc[t][q]; s2 += v * v; }
      s2 = rsum16(s2);
      float mxn = fmaxf(sqrtf(s2), MINNORM);
      float r = fast_tanh(mxn * frcp(xnq) * fast_artanh(xnq)) * frcp(mxn);
      float pn = r * mxn;
      if (pn > MAXNORM) { r *= MAXNORM * frcp(pn); pn = MAXNORM; }
      float h[8];
      float hn;
      if (bias_zero) {
#pragma unroll
        for (int t = 0; t < 8; ++t) h[t] = r * acc[t][q];
        hn = pn;
      } else {
        float xy = 0.f;
#pragma unroll
        for (int t = 0; t < 8; ++t) { h[t] = r * acc[t][q]; xy += h[t] * bfr[t]; }
        xy = rsum16(xy);
        float x2 = pn * pn;
        float ca = 1.f + 2.f * xy + y2;
        float cb = 1.f - x2;
        float id = frcp(fmaxf(1.f + 2.f * xy + x2 * y2, MINNORM));
        float s3 = 0.f;
#pragma unroll
        for (int t = 0; t < 8; ++t) { h[t] = (ca * h[t] + cb * bfr[t]) * id; s3 += h[t] * h[t]; }
        hn = fmaxf(sqrtf(rsum16(s3)), MINNORM);
      }
      float ps = (hn > MAXNORM) ? (MAXNORM * frcp(hn)) : 1.f;
      float np = fmaxf(hn * ps, MINNORM);
      float tsc = fast_artanh(np) * frcp(np) * ps;
      if (row < N) {
        u16* xo = xt + (size_t)row * D + lc;
#pragma unroll
        for (int t = 0; t < 8; ++t) xo[16 * t] = f2bf(tsc * h[t]);
      }
    }
  }
}

extern "C" __global__ __launch_bounds__(256)
void OriginHyperbolicGraphConvolution_38628935860614_kernel(
    const void* x, const void* W, const void* b, u16* xt, int N) {
  __shared__ uint4 Wh[2048];   // 32 KB
  __shared__ uint4 Wl[2048];   // 32 KB (fp32 input path only)
  if (detect_bf16((const u32*)x)) k1_body<true >(x, W, b, xt, N, Wh, Wl);
  else                            k1_body<false>(x, W, b, xt, N, Wh, Wl);
}

// ====== ksA: SINGLE edge pass -> LDS bucket sort -> slotted run-claim write ======
// Each bucket owns a fixed CAP-record slot in ebuck. Per nonzero (chunk,bucket)
// run: ONE atomicAdd on a line-padded cursor claims a contiguous range; the
// ~2.6-record run is written there. Overflow (>CAP, never hit on uniform data)
// spills to a tagged list merged by ks3. Record: x = src|dstin<<17, y = w bits.
extern "C" __global__ __launch_bounds__(256) void ksA(
    const int* ei, const void* ew, uint2* ebuck, int* cursor,
    uint2* ofl, int* oflb, int* oflcnt, int E, int N, int nb) {
  __shared__ int   hist[MAXNB];        // 4 KB
  __shared__ int   sArr[MAXNB + 1];    // 4 KB
  __shared__ int   psum[256];          // 1 KB
  __shared__ uint2 recs[CHUNK];        // 16 KB
  const bool i64 = detect_i64(ei);
  const bool bf  = detect_bf16((const u32*)ew);
  const int tid   = threadIdx.x;
  const int cbase = blockIdx.x * CHUNK;

  for (int i = tid; i < MAXNB; i += 256) hist[i] = 0;
  __syncthreads();

  int bkt[8], rank[8]; u32 px[8], wb[8]; bool val[8];
#pragma unroll
  for (int r = 0; r < 8; ++r) {
    const int e = cbase + r * 256 + tid;
    val[r] = false;
    if (e < E) {
      int dst, src;
      if (i64) {
        dst = (int)((const uint2*)ei)[(size_t)e].x;          // 8B load, low word
        src = (int)((const uint2*)ei)[(size_t)E + e].x;
      } else {
        dst = ei[e]; src = ei[(size_t)E + e];
      }
      if ((unsigned)dst < (unsigned)N && (unsigned)src < (unsigned)N) {
        val[r] = true;
        bkt[r] = dst >> BSH;
        px[r]  = (u32)src | ((u32)(dst & ((1 << BSH) - 1)) << 17);
        float w;
        if (bf) w = bf2f(((const u16*)ew)[e]); else w = ((const float*)ew)[e];
        wb[r] = __float_as_uint(w);
        rank[r] = atomicAdd(&hist[bkt[r]], 1);
      }
    }
  }
  __syncthreads();

  // exclusive scan of hist -> sArr (256 threads x 4 bins)
  const int g0 = tid * 4;
  int loc[4], ts = 0;
#pragma unroll
  for (int i = 0; i < 4; ++i) { loc[i] = ts; ts += hist[g0 + i]; }
  psum[tid] = ts; __syncthreads();
#pragma unroll
  for (int off = 1; off < 256; off <<= 1) {
    int t = (tid >= off) ? psum[tid - off] : 0;
    __syncthreads();
    psum[tid] += t;
    __syncthreads();
  }
  const int excl = psum[tid] - ts;
#pragma unroll
  for (int i = 0; i < 4; ++i) sArr[g0 + i] = excl + loc[i];
  if (tid == 255) sArr[MAXNB] = psum[255];
  __syncthreads();

  // place into LDS in bucket-sorted order
#pragma unroll
  for (int r = 0; r < 8; ++r) if (val[r])
    recs[sArr[bkt[r]] + rank[r]] = make_uint2(px[r], wb[r]);
  __syncthreads();

  // run-claim + slot write (thread per bucket; ~3 buckets, ~8 records each)
  for (int b = tid; b < nb; b += 256) {
    const int a = sArr[b], len = sArr[b + 1] - a;
    if (len == 0) continue;
    const int pos = atomicAdd(&cursor[b * CURSTRIDE], len);
    for (int j = 0; j < len; ++j) {
      const uint2 r = recs[a + j];
      const int p = pos + j;
      if (p < CAP) ebuck[(size_t)b * CAP + p] = r;
      else {
        const int op = atomicAdd(oflcnt, 1);
        if (op < OCAP) { ofl[op] = r; oflb[op] = b; }
      }
    }
  }
}

// ====== ks3: node-sort bucket slot IN PLACE + emit per-node (start,count) ======
// Block per bucket. Contiguous read of slot segment -> LDS stage + 128-node
// histogram -> scan -> offs2[node] = (global start, count) -> scatter back
// (node-sorted, src field stripped of dstin). All traffic contiguous/L2-local.
// Fallbacks: cnt > CAP -> scatter to tail region; cnt > SCAP2 -> 2-pass direct.
extern "C" __global__ __launch_bounds__(256) void ks3(
    uint2* ebuck, const int* cursor, const uint2* ofl, const int* oflb,
    const int* oflcnt, int* tailcur, uint2* offs2, int N, int nb) {
  __shared__ uint2 stage[SCAP2];       // 40 KB
  __shared__ int hist[128], sc[128], cur[128];
  __shared__ int extr, tb;
  const int tid = threadIdx.x;
  const int b = blockIdx.x;
  const int cnt = cursor[b * CURSTRIDE];
  const int inslot = min(cnt, CAP);
  uint2* seg = ebuck + (size_t)b * CAP;
  const int nof = min(*oflcnt, OCAP);
  const int node0 = b << BSH;
  if (tid < 128) hist[tid] = 0;
  if (tid == 0) extr = inslot;
  __syncthreads();

  const bool fit = (cnt <= SCAP2);
  if (fit) {
    for (int i = tid; i < inslot; i += 256) {
      const uint2 r = seg[i];
      stage[i] = r;
      atomicAdd(&hist[(r.x >> 17) & 127], 1);
    }
    if (cnt > CAP) {
      for (int i = tid; i < nof; i += 256) if (oflb[i] == b) {
        const int p = atomicAdd(&extr, 1);
        const uint2 r = ofl[i];
        stage[p] = r;
        atomicAdd(&hist[(r.x >> 17) & 127], 1);
      }
    }
  } else {
    for (int i = tid; i < inslot; i += 256)
      atomicAdd(&hist[(seg[i].x >> 17) & 127], 1);
    for (int i = tid; i < nof; i += 256) if (oflb[i] == b)
      atomicAdd(&hist[(ofl[i].x >> 17) & 127], 1);
  }
  __syncthreads();

  int v = 0;
  if (tid < 128) { v = hist[tid]; sc[tid] = v; }
  __syncthreads();
#pragma unroll
  for (int off = 1; off < 128; off <<= 1) {
    int t = (tid < 128 && tid >= off) ? sc[tid - off] : 0;
    __syncthreads();
    if (tid < 128) sc[tid] += t;
    __syncthreads();
  }
  if (tid == 0) tb = (cnt <= CAP) ? -1 : atomicAdd(tailcur, cnt);
  __syncthreads();
  const size_t base = (tb < 0) ? (size_t)b * CAP : ((size_t)nb * CAP + (size_t)tb);
  if (tid < 128) {
    const int st = sc[tid] - v;
    cur[tid] = st;
    const int node = node0 + tid;
    if (node < N) offs2[node] = make_uint2((u32)(base + st), (u32)v);
  }
  __syncthreads();

  if (fit) {
    const int tot = extr;
    for (int i = tid; i < tot; i += 256) {
      const uint2 r = stage[i];
      const int d = atomicAdd(&cur[(r.x >> 17) & 127], 1);
      ebuck[base + d] = make_uint2(r.x & 0x1FFFFu, r.y);
    }
  } else {
    for (int i = tid; i < inslot; i += 256) {
      const uint2 r = seg[i];
      const int d = atomicAdd(&cur[(r.x >> 17) & 127], 1);
      ebuck[base + d] = make_uint2(r.x & 0x1FFFFu, r.y);
    }
    for (int i = tid; i < nof; i += 256) if (oflb[i] == b) {
      const uint2 r = ofl[i];
      const int d = atomicAdd(&cur[(r.x >> 17) & 127], 1);
      ebuck[base + d] = make_uint2(r.x & 0x1FFFFu, r.y);
    }
  }
}

// ====== kagg: gather-aggregate per node + fused finalize ======
// Wave per node, register accumulation, wave-uniform s_load edge records,
// 16-deep gather ILP (VGPR headroom: round-5 build was 12 VGPR).
extern "C" __global__ __launch_bounds__(256) void kagg(
    const uint2* offs2, const uint2* ebuck, const u16* xt,
    void* out, const void* xdet, int N) {
  const bool bf = detect_bf16((const u32*)xdet);
  const int lane = threadIdx.x & 63;
  const int node = blockIdx.x * 4 + (threadIdx.x >> 6);
  if (node >= N) return;
  const uint2 oo = offs2[node];
  const int s0  = __builtin_amdgcn_readfirstlane((int)oo.x);
  const int cnt = __builtin_amdgcn_readfirstlane((int)oo.y);
  const uint2* ep = ebuck + s0;
  const u32* xtw = (const u32*)xt;
  float a0 = 0.f, a1 = 0.f;
  int i = 0;
  for (; i + 16 <= cnt; i += 16) {
    uint2 e[16]; u32 u[16];
#pragma unroll
    for (int k = 0; k < 16; ++k) e[k] = ep[i + k];           // uniform (s_load)
#pragma unroll
    for (int k = 0; k < 16; ++k) u[k] = xtw[(e[k].x << 6) | lane];  // 16 in flight
#pragma unroll
    for (int k = 0; k < 16; ++k) {
      const float w = __uint_as_float(e[k].y);
      a0 += w * bflo(u[k]);
      a1 += w * bfhi(u[k]);
    }
  }
  for (; i + 4 <= cnt; i += 4) {
    uint2 e[4]; u32 u[4];
#pragma unroll
    for (int k = 0; k < 4; ++k) e[k] = ep[i + k];
#pragma unroll
    for (int k = 0; k < 4; ++k) u[k] = xtw[(e[k].x << 6) | lane];
#pragma unroll
    for (int k = 0; k < 4; ++k) {
      const float w = __uint_as_float(e[k].y);
      a0 += w * bflo(u[k]);
      a1 += w * bfhi(u[k]);
    }
  }
  for (; i < cnt; ++i) {
    const uint2 e = ep[i];
    const u32 u = xtw[(e.x << 6) | lane];
    const float w = __uint_as_float(e.y);
    a0 += w * bflo(u);
    a1 += w * bfhi(u);
  }
  // finalize: expmap0 -> proj -> logmap0 -> relu -> expmap0 -> proj
  float n = fmaxf(sqrtf(wsum(a0 * a0 + a1 * a1)), MINNORM);
  float tn = fast_tanh(n);
  float m = tn * frcp(n);
  if (tn > MAXNORM) { m *= MAXNORM * frcp(tn); tn = MAXNORM; }
  float nn = fmaxf(tn, MINNORM);
  m *= fast_artanh(nn) * frcp(nn);
  float tA = fmaxf(m * a0, 0.f), tB = fmaxf(m * a1, 0.f);
  float nr = fmaxf(sqrtf(wsum(tA * tA + tB * tB)), MINNORM);
  float t2 = fast_tanh(nr);
  float m2 = t2 * frcp(nr);
  if (t2 > MAXNORM) m2 *= MAXNORM * frcp(t2);
  float oA = m2 * tA, oB = m2 * tB;
  if (bf) {
    u32 o = ((u32)f2bf(oA)) | (((u32)f2bf(oB)) << 16);
    ((u32*)out)[(size_t)node * 64 + lane] = o;
  } else {
    ((float2*)out)[(size_t)node * 64 + lane] = make_float2(oA, oB);
  }
}

extern "C" void kernel_launch(void* const* d_in, const int* in_sizes, int n_in,
                              void* d_out, int out_size, void* d_ws, size_t ws_size,
                              hipStream_t stream) {
  const void* x    = d_in[0];
  const void* W    = d_in[1];
  const void* bias = d_in[2];
  const int*  ei   = (const int*)d_in[3];
  const void* ew   = d_in[4];
  const int N = in_sizes[0] / D;
  const int E = in_sizes[4];
  const int nchunks = (E + CHUNK - 1) / CHUNK;
  const int nb      = (N + (1 << BSH) - 1) >> BSH;

  char* ws = (char*)d_ws;
  size_t off = 0;
  auto carve = [&](size_t bytes) { char* p = ws + off; off = (off + bytes + 255) & ~(size_t)255; return p; };
  u16*   xt    = (u16*)  carve((size_t)N * D * sizeof(u16));                 // 25.6 MB
  uint2* ebuck = (uint2*)carve(((size_t)nb * CAP + TCAP) * sizeof(uint2));   // 33.6 MB
  uint2* ofl   = (uint2*)carve((size_t)OCAP * sizeof(uint2));                // 2 MB
  int*   oflb  = (int*)  carve((size_t)OCAP * sizeof(int));                  // 1 MB
  uint2* offs2 = (uint2*)carve((size_t)N * sizeof(uint2));                   // 0.8 MB
  int*   czone = (int*)  carve(((size_t)nb * CURSTRIDE + 2) * sizeof(int));  // 50 KB
  int*   cursor  = czone;
  int*   oflcnt  = czone + (size_t)nb * CURSTRIDE;
  int*   tailcur = oflcnt + 1;

  const int nz = nb * CURSTRIDE + 2;
  const int T  = (N + 15) / 16;
  const int g1 = min((T + 3) / 4, 512);

  k0_zeroi<<<(nz + 255) / 256, 256, 0, stream>>>(czone, nz);
  OriginHyperbolicGraphConvolution_38628935860614_kernel<<<g1, 256, 0, stream>>>(
      x, W, bias, xt, N);
  ksA <<<nchunks, 256, 0, stream>>>(ei, ew, ebuck, cursor, ofl, oflb, oflcnt, E, N, nb);
  ks3 <<<nb, 256, 0, stream>>>(ebuck, cursor, ofl, oflb, oflcnt, tailcur, offs2, N, nb);
  kagg<<<(N + 3) / 4, 256, 0, stream>>>(offs2, ebuck, xt, d_out, x, N);
}